// Round 1
// baseline (660.119 us; speedup 1.0000x reference)
//
#include <hip/hip_runtime.h>

#define DIN 128
#define DOUT 64
#define NEG_SLOPE 0.2f
#define ALPHA 0.5f

__device__ __forceinline__ float lrelu(float x) { return x > 0.0f ? x : NEG_SLOPE * x; }

// order-preserving float<->uint encoding for atomicMax on floats.
// memset-0 init is below every encoded real float (every node has a self-loop,
// so every segment gets at least one real write).
__device__ __forceinline__ unsigned fenc(float f) {
    unsigned u = __float_as_uint(f);
    return (u & 0x80000000u) ? ~u : (u | 0x80000000u);
}
__device__ __forceinline__ float fdec(unsigned u) {
    unsigned b = (u & 0x80000000u) ? (u & 0x7fffffffu) : ~u;
    return __uint_as_float(b);
}

// out[i][j] = (1-ALPHA)*b1[j] + ALPHA*b2[j]
__global__ __launch_bounds__(256) void init_out_kernel(
    float* __restrict__ out, const float* __restrict__ b1,
    const float* __restrict__ b2, int n)
{
    int i = blockIdx.x * 256 + threadIdx.x;
    if (i >= n * DOUT) return;
    int j = i & (DOUT - 1);
    out[i] = (1.0f - ALPHA) * b1[j] + ALPHA * b2[j];
}

// One wave (64 lanes) per node. lane = output column (DOUT==64).
// Computes xw1, xw2 rows and the 4 attention scalars via wave reduction.
__global__ __launch_bounds__(256) void proj_kernel(
    const float* __restrict__ x,
    const float* __restrict__ W1, const float* __restrict__ W2,
    const float* __restrict__ as1, const float* __restrict__ ad1,
    const float* __restrict__ as2, const float* __restrict__ ad2,
    float* __restrict__ xw1, float* __restrict__ xw2,
    float* __restrict__ s1, float* __restrict__ d1,
    float* __restrict__ s2, float* __restrict__ d2, int n)
{
    int wave = (blockIdx.x * 256 + threadIdx.x) >> 6;
    int lane = threadIdx.x & 63;
    if (wave >= n) return;

    const float* xr = x + (size_t)wave * DIN;
    float acc1 = 0.0f, acc2 = 0.0f;
    #pragma unroll 8
    for (int k = 0; k < DIN; ++k) {
        float xv = xr[k];  // wave-uniform broadcast load
        acc1 = fmaf(xv, W1[k * DOUT + lane], acc1);
        acc2 = fmaf(xv, W2[k * DOUT + lane], acc2);
    }
    xw1[(size_t)wave * DOUT + lane] = acc1;
    xw2[(size_t)wave * DOUT + lane] = acc2;

    float v1 = acc1 * as1[lane];
    float v2 = acc1 * ad1[lane];
    float v3 = acc2 * as2[lane];
    float v4 = acc2 * ad2[lane];
    #pragma unroll
    for (int off = 32; off; off >>= 1) {
        v1 += __shfl_xor(v1, off);
        v2 += __shfl_xor(v2, off);
        v3 += __shfl_xor(v3, off);
        v4 += __shfl_xor(v4, off);
    }
    if (lane == 0) { s1[wave] = v1; d1[wave] = v2; s2[wave] = v3; d2[wave] = v4; }
}

// slot t < e: real edge (src[t], dst[t]); slot t >= e: self-loop node t-e.
__global__ __launch_bounds__(256) void max_kernel(
    const int* __restrict__ src, const int* __restrict__ dst,
    const float* __restrict__ s1, const float* __restrict__ d1,
    const float* __restrict__ s2, const float* __restrict__ d2,
    unsigned* __restrict__ m_fwd, unsigned* __restrict__ m_rev, int e, int n)
{
    int t = blockIdx.x * 256 + threadIdx.x;
    if (t >= e + n) return;
    int s, d;
    if (t < e) { s = src[t]; d = dst[t]; } else { s = d = t - e; }
    float ef = lrelu(s1[s] + d1[d]);   // fwd: grouped by d
    atomicMax(&m_fwd[d], fenc(ef));
    float er = lrelu(s2[d] + d2[s]);   // rev: a_src2[dst] + a_dst2[src], grouped by s
    atomicMax(&m_rev[s], fenc(er));
}

__global__ __launch_bounds__(256) void denom_kernel(
    const int* __restrict__ src, const int* __restrict__ dst,
    const float* __restrict__ s1, const float* __restrict__ d1,
    const float* __restrict__ s2, const float* __restrict__ d2,
    const unsigned* __restrict__ m_fwd, const unsigned* __restrict__ m_rev,
    float* __restrict__ den_fwd, float* __restrict__ den_rev, int e, int n)
{
    int t = blockIdx.x * 256 + threadIdx.x;
    if (t >= e + n) return;
    int s, d;
    if (t < e) { s = src[t]; d = dst[t]; } else { s = d = t - e; }
    float ef = lrelu(s1[s] + d1[d]);
    atomicAdd(&den_fwd[d], __expf(ef - fdec(m_fwd[d])) );
    float er = lrelu(s2[d] + d2[s]);
    atomicAdd(&den_rev[s], __expf(er - fdec(m_rev[s])) );
}

// 64 lanes per edge-slot; lane j handles column j for BOTH directions.
__global__ __launch_bounds__(256) void scatter_kernel(
    const int* __restrict__ src, const int* __restrict__ dst,
    const float* __restrict__ s1, const float* __restrict__ d1,
    const float* __restrict__ s2, const float* __restrict__ d2,
    const unsigned* __restrict__ m_fwd, const unsigned* __restrict__ m_rev,
    const float* __restrict__ den_fwd, const float* __restrict__ den_rev,
    const float* __restrict__ xw1, const float* __restrict__ xw2,
    float* __restrict__ out, int e, int n)
{
    long long tid = (long long)blockIdx.x * 256 + threadIdx.x;
    int slot = (int)(tid >> 6);
    int lane = (int)(tid & 63);
    if (slot >= e + n) return;
    int s, d;
    if (slot < e) { s = src[slot]; d = dst[slot]; } else { s = d = slot - e; }

    float ef = lrelu(s1[s] + d1[d]);
    float cf = __expf(ef - fdec(m_fwd[d])) / (den_fwd[d] + 1e-16f);
    float er = lrelu(s2[d] + d2[s]);
    float cr = __expf(er - fdec(m_rev[s])) / (den_rev[s] + 1e-16f);

    atomicAdd(&out[(size_t)d * DOUT + lane], (1.0f - ALPHA) * cf * xw1[(size_t)s * DOUT + lane]);
    atomicAdd(&out[(size_t)s * DOUT + lane], ALPHA * cr * xw2[(size_t)d * DOUT + lane]);
}

extern "C" void kernel_launch(void* const* d_in, const int* in_sizes, int n_in,
                              void* d_out, int out_size, void* d_ws, size_t ws_size,
                              hipStream_t stream) {
    const float* x   = (const float*)d_in[0];
    const int*   ei  = (const int*)d_in[1];
    const float* W1  = (const float*)d_in[2];
    const float* as1 = (const float*)d_in[3];
    const float* ad1 = (const float*)d_in[4];
    const float* b1  = (const float*)d_in[5];
    const float* W2  = (const float*)d_in[6];
    const float* as2 = (const float*)d_in[7];
    const float* ad2 = (const float*)d_in[8];
    const float* b2  = (const float*)d_in[9];
    float* out = (float*)d_out;

    int n = in_sizes[0] / DIN;   // 50000
    int e = in_sizes[1] / 2;     // 800000
    const int* src = ei;
    const int* dst = ei + e;

    // workspace layout (floats): xw1[n*64] xw2[n*64] s1 d1 s2 d2 m_fwd m_rev den_fwd den_rev
    float* ws  = (float*)d_ws;
    float* xw1 = ws;
    float* xw2 = xw1 + (size_t)n * DOUT;
    float* s1  = xw2 + (size_t)n * DOUT;
    float* d1  = s1 + n;
    float* s2  = d1 + n;
    float* d2  = s2 + n;
    unsigned* m_fwd = (unsigned*)(d2 + n);
    unsigned* m_rev = m_fwd + n;
    float* den_fwd  = (float*)(m_rev + n);
    float* den_rev  = den_fwd + n;

    // zero m_fwd, m_rev, den_fwd, den_rev (contiguous 4n words)
    hipMemsetAsync(m_fwd, 0, (size_t)4 * n * sizeof(float), stream);

    init_out_kernel<<<(n * DOUT + 255) / 256, 256, 0, stream>>>(out, b1, b2, n);

    proj_kernel<<<(n + 3) / 4, 256, 0, stream>>>(x, W1, W2, as1, ad1, as2, ad2,
                                                 xw1, xw2, s1, d1, s2, d2, n);

    int slots = e + n;
    max_kernel<<<(slots + 255) / 256, 256, 0, stream>>>(src, dst, s1, d1, s2, d2,
                                                        m_fwd, m_rev, e, n);
    denom_kernel<<<(slots + 255) / 256, 256, 0, stream>>>(src, dst, s1, d1, s2, d2,
                                                          m_fwd, m_rev, den_fwd, den_rev, e, n);

    long long sthreads = (long long)slots * 64;
    int sblocks = (int)((sthreads + 255) / 256);
    scatter_kernel<<<sblocks, 256, 0, stream>>>(src, dst, s1, d1, s2, d2,
                                                m_fwd, m_rev, den_fwd, den_rev,
                                                xw1, xw2, out, e, n);
}

// Round 3
// 553.202 us; speedup vs baseline: 1.1933x; 1.1933x over previous
//
#include <hip/hip_runtime.h>

#define DIN 128
#define DOUT 64
#define NEG_SLOPE 0.2f
#define ALPHA 0.5f

__device__ __forceinline__ float lrelu(float x) { return x > 0.0f ? x : NEG_SLOPE * x; }

// One wave (64 lanes) per node. lane = output column (DOUT==64).
// Computes xw1, xw2 rows and the 4 attention scalars via wave reduction.
__global__ __launch_bounds__(256) void proj_kernel(
    const float* __restrict__ x,
    const float* __restrict__ W1, const float* __restrict__ W2,
    const float* __restrict__ as1, const float* __restrict__ ad1,
    const float* __restrict__ as2, const float* __restrict__ ad2,
    float* __restrict__ xw1, float* __restrict__ xw2,
    float* __restrict__ s1, float* __restrict__ d1,
    float* __restrict__ s2, float* __restrict__ d2, int n)
{
    int wave = (blockIdx.x * 256 + threadIdx.x) >> 6;
    int lane = threadIdx.x & 63;
    if (wave >= n) return;

    const float* xr = x + (size_t)wave * DIN;
    float acc1 = 0.0f, acc2 = 0.0f;
    #pragma unroll 8
    for (int k = 0; k < DIN; ++k) {
        float xv = xr[k];  // wave-uniform broadcast load
        acc1 = fmaf(xv, W1[k * DOUT + lane], acc1);
        acc2 = fmaf(xv, W2[k * DOUT + lane], acc2);
    }
    xw1[(size_t)wave * DOUT + lane] = acc1;
    xw2[(size_t)wave * DOUT + lane] = acc2;

    float v1 = acc1 * as1[lane];
    float v2 = acc1 * ad1[lane];
    float v3 = acc2 * as2[lane];
    float v4 = acc2 * ad2[lane];
    #pragma unroll
    for (int off = 32; off; off >>= 1) {
        v1 += __shfl_xor(v1, off);
        v2 += __shfl_xor(v2, off);
        v3 += __shfl_xor(v3, off);
        v4 += __shfl_xor(v4, off);
    }
    if (lane == 0) { s1[wave] = v1; d1[wave] = v2; s2[wave] = v3; d2[wave] = v4; }
}

// degree histogram over real edges (self-loops handled implicitly in gather)
__global__ __launch_bounds__(256) void hist_kernel(
    const int* __restrict__ src, const int* __restrict__ dst,
    int* __restrict__ deg_fwd, int* __restrict__ deg_rev, int e)
{
    int t = blockIdx.x * 256 + threadIdx.x;
    if (t >= e) return;
    atomicAdd(&deg_fwd[dst[t]], 1);
    atomicAdd(&deg_rev[src[t]], 1);
}

// single-block exclusive scan per array. blockIdx.x in {0,1} selects
// (deg_fwd -> off_fwd) or (deg_rev -> off_rev). 1024 threads, chunked.
__global__ __launch_bounds__(1024) void scan_kernel(
    const int* __restrict__ degs, int* __restrict__ offs, int n)
{
    const int* deg = degs + (size_t)blockIdx.x * n;
    int* off = offs + (size_t)blockIdx.x * (n + 1);
    int t = threadIdx.x;
    int CH = (n + 1023) / 1024;
    int base = t * CH;

    int s = 0;
    for (int k = 0; k < CH; ++k) {
        int i = base + k;
        s += (i < n) ? deg[i] : 0;
    }
    __shared__ int sm[1024];
    sm[t] = s;
    __syncthreads();
    for (int o = 1; o < 1024; o <<= 1) {
        int v = (t >= o) ? sm[t - o] : 0;
        __syncthreads();
        sm[t] += v;
        __syncthreads();
    }
    int run = sm[t] - s;  // exclusive chunk base
    for (int k = 0; k < CH; ++k) {
        int i = base + k;
        if (i < n) { off[i] = run; run += deg[i]; }
    }
    if (t == 1023) off[n] = sm[1023];
}

__global__ __launch_bounds__(256) void fill_kernel(
    const int* __restrict__ src, const int* __restrict__ dst,
    const int* __restrict__ off_fwd, const int* __restrict__ off_rev,
    int* __restrict__ cur_fwd, int* __restrict__ cur_rev,
    int* __restrict__ csr_fwd, int* __restrict__ csr_rev, int e)
{
    int t = blockIdx.x * 256 + threadIdx.x;
    if (t >= e) return;
    int s = src[t], d = dst[t];
    int p = atomicAdd(&cur_fwd[d], 1);
    csr_fwd[off_fwd[d] + p] = s;
    int q = atomicAdd(&cur_rev[s], 1);
    csr_rev[off_rev[s] + q] = d;
}

// One wave per node. Online-softmax gather over in-edges, both directions,
// one plain 256B store per node. Self-loop seeds the accumulator.
__global__ __launch_bounds__(256) void gather_kernel(
    const int* __restrict__ off_fwd, const int* __restrict__ csr_fwd,
    const int* __restrict__ off_rev, const int* __restrict__ csr_rev,
    const float* __restrict__ s1, const float* __restrict__ d1,
    const float* __restrict__ s2, const float* __restrict__ d2,
    const float* __restrict__ xw1, const float* __restrict__ xw2,
    const float* __restrict__ b1, const float* __restrict__ b2,
    float* __restrict__ out, int n)
{
    int i = (blockIdx.x * 256 + threadIdx.x) >> 6;
    int lane = threadIdx.x & 63;
    if (i >= n) return;

    // ---- forward: softmax over {edges with dst==i} + self-loop, values xw1[src]
    float d1i = d1[i];
    float m = lrelu(s1[i] + d1i);           // self-loop score
    float l = 1.0f;
    float acc = xw1[(size_t)i * DOUT + lane];
    int beg = off_fwd[i], end = off_fwd[i + 1];
    for (int t = beg; t < end; ++t) {
        int s = csr_fwd[t];
        float sc = lrelu(s1[s] + d1i);      // wave-uniform
        float v = xw1[(size_t)s * DOUT + lane];
        if (sc > m) {                       // uniform branch
            float r = __expf(m - sc);
            acc = acc * r + v;
            l = l * r + 1.0f;
            m = sc;
        } else {
            float p = __expf(sc - m);
            acc = fmaf(p, v, acc);
            l += p;
        }
    }
    float outF = acc / (l + 1e-16f);

    // ---- reverse: softmax over {edges with src==i} + self-loop, values xw2[dst]
    float d2i = d2[i];
    m = lrelu(s2[i] + d2i);
    l = 1.0f;
    acc = xw2[(size_t)i * DOUT + lane];
    beg = off_rev[i]; end = off_rev[i + 1];
    for (int t = beg; t < end; ++t) {
        int j = csr_rev[t];
        float sc = lrelu(s2[j] + d2i);
        float v = xw2[(size_t)j * DOUT + lane];
        if (sc > m) {
            float r = __expf(m - sc);
            acc = acc * r + v;
            l = l * r + 1.0f;
            m = sc;
        } else {
            float p = __expf(sc - m);
            acc = fmaf(p, v, acc);
            l += p;
        }
    }
    float outR = acc / (l + 1e-16f);

    out[(size_t)i * DOUT + lane] =
        (1.0f - ALPHA) * (outF + b1[lane]) + ALPHA * (outR + b2[lane]);
}

extern "C" void kernel_launch(void* const* d_in, const int* in_sizes, int n_in,
                              void* d_out, int out_size, void* d_ws, size_t ws_size,
                              hipStream_t stream) {
    const float* x   = (const float*)d_in[0];
    const int*   ei  = (const int*)d_in[1];
    const float* W1  = (const float*)d_in[2];
    const float* as1 = (const float*)d_in[3];
    const float* ad1 = (const float*)d_in[4];
    const float* b1  = (const float*)d_in[5];
    const float* W2  = (const float*)d_in[6];
    const float* as2 = (const float*)d_in[7];
    const float* ad2 = (const float*)d_in[8];
    const float* b2  = (const float*)d_in[9];
    float* out = (float*)d_out;

    int n = in_sizes[0] / DIN;   // 50000
    int e = in_sizes[1] / 2;     // 800000
    const int* src = ei;
    const int* dst = ei + e;

    // workspace layout (32-bit words):
    // xw1[n*64] xw2[n*64] s1[n] d1[n] s2[n] d2[n]
    // degs[2n] curs[2n] offs[2(n+1)] csr_fwd[e] csr_rev[e]
    float* ws  = (float*)d_ws;
    float* xw1 = ws;
    float* xw2 = xw1 + (size_t)n * DOUT;
    float* s1  = xw2 + (size_t)n * DOUT;
    float* d1  = s1 + n;
    float* s2  = d1 + n;
    float* d2  = s2 + n;
    int* degs  = (int*)(d2 + n);          // deg_fwd | deg_rev (contiguous 2n)
    int* deg_fwd = degs;
    int* deg_rev = degs + n;
    int* curs  = degs + 2 * (size_t)n;    // cur_fwd | cur_rev (contiguous 2n)
    int* cur_fwd = curs;
    int* cur_rev = curs + n;
    int* offs  = curs + 2 * (size_t)n;    // off_fwd[n+1] | off_rev[n+1]
    int* off_fwd = offs;
    int* off_rev = offs + (n + 1);
    int* csr_fwd = offs + 2 * (size_t)(n + 1);
    int* csr_rev = csr_fwd + e;

    // zero degs + curs (contiguous 4n words)
    hipMemsetAsync(degs, 0, (size_t)4 * n * sizeof(int), stream);

    proj_kernel<<<(n + 3) / 4, 256, 0, stream>>>(x, W1, W2, as1, ad1, as2, ad2,
                                                 xw1, xw2, s1, d1, s2, d2, n);

    hist_kernel<<<(e + 255) / 256, 256, 0, stream>>>(src, dst, deg_fwd, deg_rev, e);
    scan_kernel<<<2, 1024, 0, stream>>>(degs, offs, n);
    fill_kernel<<<(e + 255) / 256, 256, 0, stream>>>(src, dst, off_fwd, off_rev,
                                                     cur_fwd, cur_rev, csr_fwd, csr_rev, e);

    // one wave (64 threads) per node -> n*64 threads total
    long long gthreads = (long long)n * 64;
    int gblocks = (int)((gthreads + 255) / 256);
    gather_kernel<<<gblocks, 256, 0, stream>>>(
        off_fwd, csr_fwd, off_rev, csr_rev,
        s1, d1, s2, d2, xw1, xw2, b1, b2, out, n);
}

// Round 4
// 340.567 us; speedup vs baseline: 1.9383x; 1.6244x over previous
//
#include <hip/hip_runtime.h>

#define DIN 128
#define DOUT 64
#define NEG_SLOPE 0.2f
#define ALPHA 0.5f

__device__ __forceinline__ float lrelu(float x) { return x > 0.0f ? x : NEG_SLOPE * x; }

// ---------------- proj: xw1 = x@W1, xw2 = x@W2, plus 4 per-node score dots.
// Block = 256 thr (4 waves). W1+W2 staged in LDS (64 KB), x tile (16 rows) in
// LDS (8 KB). Each wave register-tiles 4 nodes. 2 blocks/CU.
__global__ __launch_bounds__(256) void proj_kernel(
    const float* __restrict__ x,
    const float* __restrict__ W1, const float* __restrict__ W2,
    const float* __restrict__ as1, const float* __restrict__ ad1,
    const float* __restrict__ as2, const float* __restrict__ ad2,
    float* __restrict__ xw1, float* __restrict__ xw2,
    float* __restrict__ s1, float* __restrict__ d1,
    float* __restrict__ s2, float* __restrict__ d2, int n)
{
    __shared__ float w1s[DIN * DOUT];   // 32 KB
    __shared__ float w2s[DIN * DOUT];   // 32 KB
    __shared__ float xs[16][DIN];       // 8 KB
    int tid = threadIdx.x;

    {   // stage W1, W2: 2048 float4 each, 8 per thread
        const float4* W14 = (const float4*)W1;
        const float4* W24 = (const float4*)W2;
        float4* w1s4 = (float4*)w1s;
        float4* w2s4 = (float4*)w2s;
        #pragma unroll
        for (int r = 0; r < 8; ++r) {
            int i = r * 256 + tid;
            w1s4[i] = W14[i];
            w2s4[i] = W24[i];
        }
    }
    int nb0 = blockIdx.x * 16;
    {   // stage x tile: 16 rows x 128 = 512 float4, 2 per thread
        const float4* x4 = (const float4*)(x + (size_t)nb0 * DIN);
        float4* xs4 = (float4*)&xs[0][0];
        int lim = (n - nb0) * (DIN / 4);
        if (lim > 512) lim = 512;
        #pragma unroll
        for (int r = 0; r < 2; ++r) {
            int i = r * 256 + tid;
            if (i < lim) xs4[i] = x4[i];
        }
    }
    __syncthreads();

    int wave = tid >> 6, lane = tid & 63;
    int nb = nb0 + wave * 4;
    float a1[4] = {0, 0, 0, 0}, a2[4] = {0, 0, 0, 0};
    #pragma unroll 4
    for (int k = 0; k < DIN; ++k) {
        float w1 = w1s[k * DOUT + lane];   // 2-way bank alias: free
        float w2 = w2s[k * DOUT + lane];
        #pragma unroll
        for (int m = 0; m < 4; ++m) {
            float xv = xs[wave * 4 + m][k];  // broadcast read: free
            a1[m] = fmaf(xv, w1, a1[m]);
            a2[m] = fmaf(xv, w2, a2[m]);
        }
    }
    float A1 = as1[lane], A2 = ad1[lane], A3 = as2[lane], A4 = ad2[lane];
    #pragma unroll
    for (int m = 0; m < 4; ++m) {
        int node = nb + m;
        if (node >= n) break;
        xw1[(size_t)node * DOUT + lane] = a1[m];
        xw2[(size_t)node * DOUT + lane] = a2[m];
        float v1 = a1[m] * A1, v2 = a1[m] * A2, v3 = a2[m] * A3, v4 = a2[m] * A4;
        #pragma unroll
        for (int off = 32; off; off >>= 1) {
            v1 += __shfl_xor(v1, off);
            v2 += __shfl_xor(v2, off);
            v3 += __shfl_xor(v3, off);
            v4 += __shfl_xor(v4, off);
        }
        if (lane == 0) { s1[node] = v1; d1[node] = v2; s2[node] = v3; d2[node] = v4; }
    }
}

// ---------------- CSR build over unified 2n segment space:
// segment i in [0,n)   : in-edges of node i  (fwd, grouped by dst)
// segment n+i          : out-edges of node i (rev, grouped by src)
__global__ __launch_bounds__(256) void hist_kernel(
    const int* __restrict__ src, const int* __restrict__ dst,
    int* __restrict__ deg, int e, int n)
{
    int t = blockIdx.x * 256 + threadIdx.x;
    if (t >= e) return;
    atomicAdd(&deg[dst[t]], 1);
    atomicAdd(&deg[n + src[t]], 1);
}

// per-1024-elem tile sums
__global__ __launch_bounds__(256) void scan_part_kernel(
    const int* __restrict__ deg, int* __restrict__ part, int n2)
{
    __shared__ int sm[256];
    int b = blockIdx.x, t = threadIdx.x;
    int base = b * 1024 + t * 4;
    int s = 0;
    #pragma unroll
    for (int k = 0; k < 4; ++k) { int i = base + k; if (i < n2) s += deg[i]; }
    sm[t] = s; __syncthreads();
    for (int o = 128; o; o >>= 1) { if (t < o) sm[t] += sm[t + o]; __syncthreads(); }
    if (t == 0) part[b] = sm[0];
}

// exclusive scan of tile sums (single block); also writes offs[n2] = total
__global__ __launch_bounds__(1024) void scan_mid_kernel(
    int* __restrict__ part, int nb, int* __restrict__ offs, int n2, int total)
{
    __shared__ int sm[1024];
    int t = threadIdx.x;
    int v = (t < nb) ? part[t] : 0;
    sm[t] = v; __syncthreads();
    for (int o = 1; o < 1024; o <<= 1) {
        int u = (t >= o) ? sm[t - o] : 0;
        __syncthreads();
        sm[t] += u;
        __syncthreads();
    }
    if (t < nb) part[t] = sm[t] - v;   // exclusive
    if (t == 0) offs[n2] = total;
}

// block-local exclusive scan + tile base -> offsets
__global__ __launch_bounds__(256) void scan_apply_kernel(
    const int* __restrict__ deg, const int* __restrict__ part,
    int* __restrict__ offs, int n2)
{
    __shared__ int sm[256];
    int b = blockIdx.x, t = threadIdx.x;
    int base = b * 1024 + t * 4;
    int d[4]; int s = 0;
    #pragma unroll
    for (int k = 0; k < 4; ++k) { int i = base + k; d[k] = (i < n2) ? deg[i] : 0; s += d[k]; }
    sm[t] = s; __syncthreads();
    for (int o = 1; o < 256; o <<= 1) {
        int u = (t >= o) ? sm[t - o] : 0;
        __syncthreads();
        sm[t] += u;
        __syncthreads();
    }
    int run = part[b] + sm[t] - s;
    #pragma unroll
    for (int k = 0; k < 4; ++k) {
        int i = base + k;
        if (i < n2) { offs[i] = run; run += d[k]; }
    }
}

__global__ __launch_bounds__(256) void fill_kernel(
    const int* __restrict__ src, const int* __restrict__ dst,
    const int* __restrict__ offs, int* __restrict__ cur,
    int* __restrict__ csr, int e, int n)
{
    int t = blockIdx.x * 256 + threadIdx.x;
    if (t >= e) return;
    int s = src[t], d = dst[t];
    int p = atomicAdd(&cur[d], 1);
    csr[offs[d] + p] = s;
    int q = atomicAdd(&cur[n + s], 1);
    csr[offs[n + s] + q] = d;
}

// ---------------- gather: 2 waves per node (one per direction), branchless
// online softmax, one 256B atomicAdd per (node, dir) onto zeroed out.
__global__ __launch_bounds__(256) void gather_kernel(
    const int* __restrict__ offs, const int* __restrict__ csr,
    const float* __restrict__ s1, const float* __restrict__ d1,
    const float* __restrict__ s2, const float* __restrict__ d2,
    const float* __restrict__ xw1, const float* __restrict__ xw2,
    const float* __restrict__ b1, const float* __restrict__ b2,
    float* __restrict__ out, int n)
{
    int w = (blockIdx.x * 256 + threadIdx.x) >> 6;
    int lane = threadIdx.x & 63;
    if (w >= 2 * n) return;
    int i = w >> 1;
    int dir = w & 1;

    const float* sbuf = dir ? s2 : s1;
    const float* xw   = dir ? xw2 : xw1;
    float dsc = dir ? d2[i] : d1[i];
    int base = dir ? n + i : i;
    int beg = offs[base], end = offs[base + 1];

    // self-loop seeds the running softmax
    float m = lrelu(sbuf[i] + dsc);
    float l = 1.0f;
    float acc = xw[(size_t)i * DOUT + lane];

    #pragma unroll 2
    for (int t = beg; t < end; ++t) {
        int j = csr[t];
        float sc = lrelu(sbuf[j] + dsc);     // wave-uniform
        float v = xw[(size_t)j * DOUT + lane];
        float mn = fmaxf(m, sc);
        float r = __expf(m - mn);            // == 1.0 exactly when m >= sc
        float p = __expf(sc - mn);
        acc = fmaf(p, v, acc * r);
        l   = fmaf(l, r, p);
        m = mn;
    }
    float res = acc / (l + 1e-16f);
    float add;
    if (dir) add = ALPHA * res;
    else     add = (1.0f - ALPHA) * res + (1.0f - ALPHA) * b1[lane] + ALPHA * b2[lane];
    atomicAdd(&out[(size_t)i * DOUT + lane], add);
}

extern "C" void kernel_launch(void* const* d_in, const int* in_sizes, int n_in,
                              void* d_out, int out_size, void* d_ws, size_t ws_size,
                              hipStream_t stream) {
    const float* x   = (const float*)d_in[0];
    const int*   ei  = (const int*)d_in[1];
    const float* W1  = (const float*)d_in[2];
    const float* as1 = (const float*)d_in[3];
    const float* ad1 = (const float*)d_in[4];
    const float* b1  = (const float*)d_in[5];
    const float* W2  = (const float*)d_in[6];
    const float* as2 = (const float*)d_in[7];
    const float* ad2 = (const float*)d_in[8];
    const float* b2  = (const float*)d_in[9];
    float* out = (float*)d_out;

    int n = in_sizes[0] / DIN;   // 50000
    int e = in_sizes[1] / 2;     // 800000
    const int* src = ei;
    const int* dst = ei + e;
    int n2 = 2 * n;
    int nb = (n2 + 1023) / 1024;  // 98 tiles

    // workspace (32-bit words):
    // xw1[64n] xw2[64n] s1[n] d1[n] s2[n] d2[n] deg[2n] cur[2n] offs[2n+1] part[1024] csr[2e]
    float* ws  = (float*)d_ws;
    float* xw1 = ws;
    float* xw2 = xw1 + (size_t)n * DOUT;
    float* s1  = xw2 + (size_t)n * DOUT;
    float* d1  = s1 + n;
    float* s2  = d1 + n;
    float* d2  = s2 + n;
    int* deg   = (int*)(d2 + n);
    int* cur   = deg + (size_t)n2;
    int* offs  = cur + (size_t)n2;
    int* part  = offs + (size_t)n2 + 1;
    int* csr   = part + 1024;

    hipMemsetAsync(deg, 0, (size_t)2 * n2 * sizeof(int), stream);      // deg + cur
    hipMemsetAsync(out, 0, (size_t)n * DOUT * sizeof(float), stream);

    proj_kernel<<<(n + 15) / 16, 256, 0, stream>>>(x, W1, W2, as1, ad1, as2, ad2,
                                                   xw1, xw2, s1, d1, s2, d2, n);

    hist_kernel<<<(e + 255) / 256, 256, 0, stream>>>(src, dst, deg, e, n);
    scan_part_kernel<<<nb, 256, 0, stream>>>(deg, part, n2);
    scan_mid_kernel<<<1, 1024, 0, stream>>>(part, nb, offs, n2, 2 * e);
    scan_apply_kernel<<<nb, 256, 0, stream>>>(deg, part, offs, n2);
    fill_kernel<<<(e + 255) / 256, 256, 0, stream>>>(src, dst, offs, cur, csr, e, n);

    long long gthreads = (long long)n2 * 64;
    int gblocks = (int)((gthreads + 255) / 256);
    gather_kernel<<<gblocks, 256, 0, stream>>>(offs, csr, s1, d1, s2, d2,
                                               xw1, xw2, b1, b2, out, n);
}